// Round 9
// baseline (257.549 us; speedup 1.0000x reference)
//
#include <hip/hip_runtime.h>
#include <hip/hip_bf16.h>

typedef __attribute__((ext_vector_type(8))) short bf16x8;
typedef __attribute__((ext_vector_type(4))) float f32x4;
typedef __attribute__((ext_vector_type(16))) float f32x16;
typedef __attribute__((ext_vector_type(4))) short short4v;
typedef __attribute__((ext_vector_type(4))) unsigned u32x4;

__device__ __forceinline__ unsigned short f2bf(float f) {
  union { float f; unsigned u; } x; x.f = f;
  return (unsigned short)((x.u + 0x7FFFu + ((x.u >> 16) & 1u)) >> 16);
}

__device__ __forceinline__ short f2bf_hw(float f) {
  __hip_bfloat16 h = __float2bfloat16(f);
  return *(short*)&h;
}

__device__ __forceinline__ unsigned pk2(float a, float b) {
  float2 t2; t2.x = a; t2.y = b;
  __hip_bfloat162 t = __float22bfloat162_rn(t2);
  return *(unsigned*)&t;
}

__device__ __forceinline__ void lds_cp16(const void* g, void* l) {
  __builtin_amdgcn_global_load_lds(
      (const __attribute__((address_space(1))) void*)g,
      (__attribute__((address_space(3))) void*)l,
      16, 0, 0);
}

#define GBAR() do { __builtin_amdgcn_s_barrier(); __builtin_amdgcn_sched_barrier(0); } while (0)

// ---------------- cast fp32 -> bf16, vectorized ----------------
__global__ __launch_bounds__(256) void cast_x(const float* __restrict__ in,
                                              short* __restrict__ out, int n4) {
  int i = blockIdx.x * 256 + threadIdx.x;
  if (i >= n4) return;
  float4 v = reinterpret_cast<const float4*>(in)[i];
  short4v o;
  o.x = (short)f2bf(v.x); o.y = (short)f2bf(v.y);
  o.z = (short)f2bf(v.z); o.w = (short)f2bf(v.w);
  reinterpret_cast<short4v*>(out)[i] = o;
}

// ---------------- transpose + cast: in KxN fp32 -> out NxK bf16 ----------------
__global__ __launch_bounds__(256) void transp_cast(const float* __restrict__ in,
                                                   short* __restrict__ out,
                                                   int K, int N) {
  __shared__ float t[32][33];
  int bn = blockIdx.x * 32, bk = blockIdx.y * 32;
  int tx = threadIdx.x, ty = threadIdx.y;
  for (int i = ty; i < 32; i += 8)
    t[i][tx] = in[(size_t)(bk + i) * N + bn + tx];
  __syncthreads();
  for (int i = ty; i < 32; i += 8)
    out[(size_t)(bn + i) * K + bk + tx] = (short)f2bf(t[tx][i]);
}

// ---------------- bf16 transpose: per head [2048 pos][128 dh] -> [128 dh][2048 pos]
__global__ __launch_bounds__(256) void transp_v(const short* __restrict__ V,
                                                short* __restrict__ VTo) {
  __shared__ short t[32][34];
  const int hd = blockIdx.z;
  const int p0 = blockIdx.x * 32, d0 = blockIdx.y * 32;
  const short* src = V + (size_t)hd * 2048 * 128;
  short* dst = VTo + (size_t)hd * 2048 * 128;
  int tx = threadIdx.x, ty = threadIdx.y;
  for (int i = ty; i < 32; i += 8)
    t[i][tx] = src[(size_t)(p0 + i) * 128 + d0 + tx];
  __syncthreads();
  for (int i = ty; i < 32; i += 8)
    dst[(size_t)(d0 + i) * 2048 + p0 + tx] = t[tx][i];
}

// ---------------- 8-wave deep-phase GEMM (unchanged from round 6) ------------
template <int BM, int EPI>
__global__ __launch_bounds__(512, 2) void gemm8p(
    const short* __restrict__ A, const short* __restrict__ Bt,
    float* __restrict__ C,
    short* __restrict__ Qo, short* __restrict__ Ko, short* __restrict__ Vo,
    const float* __restrict__ cosT, const float* __restrict__ sinT,
    int N, int Kd, int nbm) {
  constexpr int NM = BM / 64;
  __shared__ __align__(16) short As[2][BM * 64];
  __shared__ __align__(16) short Bs[2][256 * 64];
  const int tid = threadIdx.x;
  const int l = tid & 63, l15 = l & 15, l4 = l >> 4;
  const int wid = tid >> 6, wr = wid >> 1, wc = wid & 1;
  const int cpx = gridDim.x >> 3;
  const int sid = (blockIdx.x & 7) * cpx + (blockIdx.x >> 3);
  const int bm = sid % nbm, bn = sid / nbm;

  const int srow = tid >> 3;
  const int sch = tid & 7;

  auto stA = [&](int dbuf, int k0, int i) {
    const int rl = srow + i * 64;
    const int c = sch ^ (rl & 7);
    lds_cp16(A + (size_t)(bm * BM + rl) * Kd + k0 + c * 8,
             (char*)As[dbuf] + tid * 16 + i * 8192);
  };
  auto stB = [&](int dbuf, int k0, int j) {
    const int rl = srow + j * 64;
    const int c = sch ^ (rl & 7);
    lds_cp16(Bt + (size_t)(bn * 256 + rl) * Kd + k0 + c * 8,
             (char*)Bs[dbuf] + tid * 16 + j * 8192);
  };
  auto rdA = [&](int dbuf, int m, int kb) {
    const int row = wr * (BM / 4) + m * 16 + l15;
    return *(const bf16x8*)((const char*)As[dbuf] + (row << 7) +
                            ((kb * 64 + l4 * 16) ^ ((row & 7) << 4)));
  };
  auto rdB = [&](int dbuf, int nh, int f, int kb) {
    const int row = wc * 128 + nh * 64 + f * 16 + l15;
    return *(const bf16x8*)((const char*)Bs[dbuf] + (row << 7) +
                            ((kb * 64 + l4 * 16) ^ ((row & 7) << 4)));
  };

  f32x4 acc[NM][8];
#pragma unroll
  for (int m = 0; m < NM; m++)
#pragma unroll
    for (int n = 0; n < 8; n++) acc[m][n] = (f32x4){0.f, 0.f, 0.f, 0.f};

  const int NT = Kd >> 6;

#pragma unroll
  for (int i = 0; i < NM; i++) stA(0, 0, i);
#pragma unroll
  for (int j = 0; j < 4; j++) stB(0, 0, j);
  asm volatile("s_waitcnt vmcnt(0)" ::: "memory");
  GBAR();

  for (int kt = 0; kt < NT; kt++) {
    const int buf = kt & 1, nbf = buf ^ 1;
    const bool stg = (kt + 1 < NT);
    const int k1 = (kt + 1) << 6;
    bf16x8 a[NM], b[4];

    // ---------- phase 0 ----------
#pragma unroll
    for (int m = 0; m < NM; m++) a[m] = rdA(buf, m, 0);
#pragma unroll
    for (int f = 0; f < 4; f++) b[f] = rdB(buf, 0, f, 0);
    if (stg) { stA(nbf, k1, 0); stA(nbf, k1, 1); }
    if (stg) asm volatile("s_waitcnt vmcnt(2)" ::: "memory");
    else     asm volatile("s_waitcnt vmcnt(0)" ::: "memory");
    GBAR();
    asm volatile("s_waitcnt lgkmcnt(0)" ::: "memory");
    __builtin_amdgcn_sched_barrier(0);
    __builtin_amdgcn_s_setprio(1);
#pragma unroll
    for (int m = 0; m < NM; m++)
#pragma unroll
      for (int f = 0; f < 4; f++)
        acc[m][f] = __builtin_amdgcn_mfma_f32_16x16x32_bf16(a[m], b[f], acc[m][f], 0, 0, 0);
    __builtin_amdgcn_s_setprio(0);
    GBAR();

    // ---------- phase 1 ----------
#pragma unroll
    for (int f = 0; f < 4; f++) b[f] = rdB(buf, 1, f, 0);
    if (stg) {
      if (BM == 256) { stA(nbf, k1, 2); stA(nbf, k1, 3); }
      else           { stB(nbf, k1, 0); stB(nbf, k1, 2); }
    }
    GBAR();
    asm volatile("s_waitcnt lgkmcnt(0)" ::: "memory");
    __builtin_amdgcn_sched_barrier(0);
    __builtin_amdgcn_s_setprio(1);
#pragma unroll
    for (int m = 0; m < NM; m++)
#pragma unroll
      for (int f = 0; f < 4; f++)
        acc[m][4 + f] = __builtin_amdgcn_mfma_f32_16x16x32_bf16(a[m], b[f], acc[m][4 + f], 0, 0, 0);
    __builtin_amdgcn_s_setprio(0);
    GBAR();

    // ---------- phase 2 ----------
#pragma unroll
    for (int m = 0; m < NM; m++) a[m] = rdA(buf, m, 1);
#pragma unroll
    for (int f = 0; f < 4; f++) b[f] = rdB(buf, 0, f, 1);
    if (stg) {
      if (BM == 256) { stB(nbf, k1, 0); stB(nbf, k1, 2); }
      else           { stB(nbf, k1, 1); stB(nbf, k1, 3); }
    }
    GBAR();
    asm volatile("s_waitcnt lgkmcnt(0)" ::: "memory");
    __builtin_amdgcn_sched_barrier(0);
    __builtin_amdgcn_s_setprio(1);
#pragma unroll
    for (int m = 0; m < NM; m++)
#pragma unroll
      for (int f = 0; f < 4; f++)
        acc[m][f] = __builtin_amdgcn_mfma_f32_16x16x32_bf16(a[m], b[f], acc[m][f], 0, 0, 0);
    __builtin_amdgcn_s_setprio(0);
    GBAR();

    // ---------- phase 3 ----------
#pragma unroll
    for (int f = 0; f < 4; f++) b[f] = rdB(buf, 1, f, 1);
    if (stg && BM == 256) { stB(nbf, k1, 1); stB(nbf, k1, 3); }
    if (stg) asm volatile("s_waitcnt vmcnt(2)" ::: "memory");
    GBAR();
    asm volatile("s_waitcnt lgkmcnt(0)" ::: "memory");
    __builtin_amdgcn_sched_barrier(0);
    __builtin_amdgcn_s_setprio(1);
#pragma unroll
    for (int m = 0; m < NM; m++)
#pragma unroll
      for (int f = 0; f < 4; f++)
        acc[m][4 + f] = __builtin_amdgcn_mfma_f32_16x16x32_bf16(a[m], b[f], acc[m][4 + f], 0, 0, 0);
    __builtin_amdgcn_s_setprio(0);
    GBAR();
  }

  if (EPI == 0) {
#pragma unroll
    for (int m = 0; m < NM; m++) {
      const int grow = bm * BM + wr * (BM / 4) + m * 16 + l4 * 4;
#pragma unroll
      for (int ni = 0; ni < 8; ni++) {
        const int col = bn * 256 + wc * 128 + (ni >> 2) * 64 + (ni & 3) * 16 + l15;
#pragma unroll
        for (int r = 0; r < 4; r++)
          C[(size_t)(grow + r) * N + col] = acc[m][ni][r];
      }
    }
  } else {
    const int head = bn * 2 + wc;
#pragma unroll
    for (int m = 0; m < NM; m++) {
#pragma unroll
      for (int r = 0; r < 4; r++) {
        const int grow = bm * BM + wr * (BM / 4) + m * 16 + l4 * 4 + r;
        const int bb = grow >> 11, pos = grow & 2047;
        if (head < 20) {
          float c4[4], s4[4];
#pragma unroll
          for (int ni = 0; ni < 4; ni++) {
            const int dh = ni * 16 + l15;
            c4[ni] = cosT[pos * 128 + dh];
            s4[ni] = sinT[pos * 128 + dh];
          }
          short* dst;
          if (head < 16) dst = Qo + ((size_t)(bb * 16 + head) * 2048 + pos) * 128;
          else           dst = Ko + ((size_t)(bb * 4 + (head - 16)) * 2048 + pos) * 128;
#pragma unroll
          for (int ni = 0; ni < 4; ni++) {
            const int dh = ni * 16 + l15;
            float xlo = acc[m][ni][r], xhi = acc[m][ni + 4][r];
            dst[dh]      = (short)f2bf(xlo * c4[ni] - xhi * s4[ni]);
            dst[dh + 64] = (short)f2bf(xhi * c4[ni] + xlo * s4[ni]);
          }
        } else {
          short* dst = Vo + ((size_t)(bb * 4 + (head - 20)) * 2048 + pos) * 128;
#pragma unroll
          for (int ni = 0; ni < 8; ni++)
            dst[(ni >> 2) * 64 + (ni & 3) * 16 + l15] = (short)f2bf(acc[m][ni][r]);
        }
      }
    }
  }
}

// ---------------- flash attention, causal, GQA — 32x32 MFMA + kv-split ------
// 512 blocks x 4 waves (256 thr). Block owns uniform pair (pp, 31-pp), 64
// q-rows per tile-pass. Wave (qh=w&1, kh=w>>1): 32q x 32k slice of each
// 64-key tile. Swapped QK^T + in-register P transform (round-8 verified).
// No-max softmax => kv-halves merge by pure ADD at the end (LDS, one-time).
// dbuf global_load_lds staging, pre-swizzled source, XOR (row&7)<<4.
__global__ __launch_bounds__(256) void attn_fwd(
    const short* __restrict__ Q, const short* __restrict__ K,
    const short* __restrict__ VT, short* __restrict__ AO) {
  __shared__ __align__(16) short Ks[2][64 * 128];
  __shared__ __align__(16) short VTs[2][128 * 64];
  const int tid = threadIdx.x;
  const int w = tid >> 6, l = tid & 63;
  const int l31 = l & 31, hi = l >> 5;
  const int qh = w & 1, kh = w >> 1;
  const int bid = blockIdx.x;
  const int lg = (bid & 7) * 64 + (bid >> 3);   // XCD-chunked logical id
  const int bh = lg >> 4, pp = lg & 15;
  const int b = bh >> 4, h = bh & 15, kv = h >> 2;
  const short* Qbase = Q + (size_t)(b * 16 + h) * 2048 * 128;
  const short* Kbase = K + (size_t)(b * 4 + kv) * 2048 * 128;
  const short* VTb   = VT + (size_t)(b * 4 + kv) * 2048 * 128;

  // staging (256 thr, 4 cp16 each for K and V^T), pre-swizzled source chunk
  int koff[4], voff[4];
#pragma unroll
  for (int i = 0; i < 4; i++) {
    const int c = tid + i * 256;
    const int rk = c >> 4, ck = (c & 15) ^ (rk & 7);
    const int dv = c >> 3, kc = (c & 7) ^ (dv & 7);
    koff[i] = rk * 128 + ck * 8;
    voff[i] = dv * 2048 + kc * 8;
  }

  const float SCL = 0.08838834764831845f * 1.4426950408889634f;  // 1/sqrt(128)*log2e
  bf16x8 ones;
#pragma unroll
  for (int j = 0; j < 8; j++) ones[j] = (short)0x3F80;

  for (int qq = 0; qq < 2; qq++) {
    const int qt = qq ? (31 - pp) : pp;
    const int q0w = qt * 64 + qh * 32;

    bf16x8 qf[8];
#pragma unroll
    for (int kb = 0; kb < 8; kb++)
      qf[kb] = *(const bf16x8*)(Qbase + (size_t)(q0w + l31) * 128 + kb * 16 + hi * 8);

    f32x16 oacc[4];
#pragma unroll
    for (int nb = 0; nb < 4; nb++)
#pragma unroll
      for (int r = 0; r < 16; r++) oacc[nb][r] = 0.f;
    f32x16 lacc;
#pragma unroll
    for (int r = 0; r < 16; r++) lacc[r] = 0.f;

    const int ntiles = qt + 1;

    __syncthreads();  // prior pass's LDS use (incl. combine buffer) done
#pragma unroll
    for (int i = 0; i < 4; i++) {
      lds_cp16(Kbase + koff[i], (char*)Ks[0] + i * 4096 + tid * 16);
      lds_cp16(VTb + voff[i],   (char*)VTs[0] + i * 4096 + tid * 16);
    }

    for (int nt = 0; nt < ntiles; nt++) {
      const int k0 = nt * 64, buf = nt & 1;
      __syncthreads();  // drains own vmcnt -> tile nt resident for all waves
      if (nt + 1 < ntiles) {
        const int kn = k0 + 64, bnx = buf ^ 1;
#pragma unroll
        for (int i = 0; i < 4; i++) {
          lds_cp16(Kbase + (size_t)kn * 128 + koff[i], (char*)Ks[bnx] + i * 4096 + tid * 16);
          lds_cp16(VTb + kn + voff[i],                 (char*)VTs[bnx] + i * 4096 + tid * 16);
        }
      }

      const int kw0 = k0 + kh * 32;        // this wave's 32-key slice
      if (kw0 <= q0w + 31) {               // skip fully-masked slices
        // S^T = K @ Q^T: C col = q = l31, row = key_local = crow(r,hi)
        f32x16 sa;
#pragma unroll
        for (int r = 0; r < 16; r++) sa[r] = 0.f;
        __builtin_amdgcn_s_setprio(1);
        {
          const int row = kh * 32 + l31;
          const int swz = (row & 7) << 4;
#pragma unroll
          for (int kb = 0; kb < 8; kb++) {
            const char* kp = (const char*)Ks[buf] + row * 256 + ((kb * 32 + hi * 16) ^ swz);
            sa = __builtin_amdgcn_mfma_f32_32x32x16_bf16(*(const bf16x8*)kp, qf[kb], sa, 0, 0, 0);
          }
        }
        __builtin_amdgcn_s_setprio(0);

        // P = exp(s*scale); mask the diagonal slice
        const bool domask = (kw0 + 31 > q0w);
        const int qrow = q0w + l31;
#pragma unroll
        for (int r = 0; r < 16; r++) {
          float pv = exp2f(sa[r] * SCL);
          if (domask) {
            const int key = kw0 + (r & 3) + 8 * (r >> 2) + 4 * hi;
            if (key > qrow) pv = 0.f;
          }
          sa[r] = pv;
        }

        // P -> A-fragments in registers (round-8 verified transform, kg==0)
        bf16x8 pa[2];
#pragma unroll
        for (int ks = 0; ks < 2; ks++) {
          const int r0 = ks * 8;
          unsigned X = pk2(sa[r0 + 0], sa[r0 + 1]);
          unsigned Y = pk2(sa[r0 + 2], sa[r0 + 3]);
          unsigned Z = pk2(sa[r0 + 4], sa[r0 + 5]);
          unsigned W = pk2(sa[r0 + 6], sa[r0 + 7]);
          unsigned s0 = hi ? X : Z, s1 = hi ? Y : W;
          unsigned g0 = (unsigned)__shfl((int)s0, l ^ 32);
          unsigned g1 = (unsigned)__shfl((int)s1, l ^ 32);
          u32x4 pw;
          pw.x = hi ? g0 : X;
          pw.y = hi ? g1 : Y;
          pw.z = hi ? Z : g0;
          pw.w = hi ? W : g1;
          pa[ks] = *(bf16x8*)&pw;
        }

        // O += P @ V^T ; l += P @ ones   (keys kw0..kw0+31)
        __builtin_amdgcn_s_setprio(1);
#pragma unroll
        for (int nb = 0; nb < 4; nb++) {
          const int row = nb * 32 + l31;
          const int swz = (row & 7) << 4;
#pragma unroll
          for (int ks = 0; ks < 2; ks++) {
            const char* vp = (const char*)VTs[buf] + row * 128 +
                             ((kh * 64 + ks * 32 + hi * 16) ^ swz);
            oacc[nb] = __builtin_amdgcn_mfma_f32_32x32x16_bf16(pa[ks], *(const bf16x8*)vp, oacc[nb], 0, 0, 0);
          }
        }
        lacc = __builtin_amdgcn_mfma_f32_32x32x16_bf16(pa[0], ones, lacc, 0, 0, 0);
        lacc = __builtin_amdgcn_mfma_f32_32x32x16_bf16(pa[1], ones, lacc, 0, 0, 0);
        __builtin_amdgcn_s_setprio(0);
      }
    }

    // ---- merge kv-halves: kh=1 stores partials to LDS, kh=0 adds ----
    __syncthreads();
    float* cb = qh ? (float*)VTs : (float*)Ks;   // 20KB per q-half region
    if (kh == 1) {
      f32x4* d = (f32x4*)cb + l * 20;
#pragma unroll
      for (int nb = 0; nb < 4; nb++)
#pragma unroll
        for (int j = 0; j < 4; j++)
          d[nb * 4 + j] = ((f32x4*)&oacc[nb])[j];
#pragma unroll
      for (int j = 0; j < 4; j++) d[16 + j] = ((f32x4*)&lacc)[j];
    }
    __syncthreads();
    if (kh == 0) {
      const f32x4* s = (const f32x4*)cb + l * 20;
#pragma unroll
      for (int nb = 0; nb < 4; nb++)
#pragma unroll
        for (int j = 0; j < 4; j++) {
          f32x4 t = s[nb * 4 + j];
#pragma unroll
          for (int e = 0; e < 4; e++) oacc[nb][j * 4 + e] += t[e];
        }
#pragma unroll
      for (int j = 0; j < 4; j++) {
        f32x4 t = s[16 + j];
#pragma unroll
        for (int e = 0; e < 4; e++) lacc[j * 4 + e] += t[e];
      }

      // epilogue: q = q0w + crow(r,hi), d = nb*32 + l31
#pragma unroll
      for (int r = 0; r < 16; r++) {
        const float inv = 1.0f / lacc[r];
        const int q = q0w + (r & 3) + 8 * (r >> 2) + 4 * hi;
        const size_t rowb = ((size_t)b * 2048 + q) * 2048 + h * 128;
#pragma unroll
        for (int nb = 0; nb < 4; nb++)
          AO[rowb + nb * 32 + l31] = f2bf_hw(oacc[nb][r] * inv);
      }
    }
  }
}

extern "C" void kernel_launch(void* const* d_in, const int* in_sizes, int n_in,
                              void* d_out, int out_size, void* d_ws, size_t ws_size,
                              hipStream_t stream) {
  const float* hs   = (const float*)d_in[0];
  const float* cosT = (const float*)d_in[1];
  const float* sinT = (const float*)d_in[2];
  const float* Wq   = (const float*)d_in[3];
  const float* Wk   = (const float*)d_in[4];
  const float* Wv   = (const float*)d_in[5];
  const float* Wo   = (const float*)d_in[6];
  float* out = (float*)d_out;

  char* p = (char*)d_ws;
  short* Xb   = (short*)p; p += (size_t)4096 * 2048 * 2;   // reused as AO
  short* Wqkv = (short*)p; p += (size_t)3072 * 2048 * 2;
  short* Wot  = (short*)p; p += (size_t)2048 * 2048 * 2;
  short* Qb   = (short*)p; p += (size_t)2 * 16 * 2048 * 128 * 2;
  short* Kb   = (short*)p; p += (size_t)2 * 4 * 2048 * 128 * 2;
  short* Vb   = (short*)p; p += (size_t)2 * 4 * 2048 * 128 * 2;
  short* VTb  = (short*)p; p += (size_t)2 * 4 * 2048 * 128 * 2;
  short* AO   = Xb;

  cast_x<<<8192, 256, 0, stream>>>(hs, Xb, 2097152);
  transp_cast<<<dim3(64, 64), dim3(32, 8), 0, stream>>>(Wq, Wqkv, 2048, 2048);
  transp_cast<<<dim3(16, 64), dim3(32, 8), 0, stream>>>(Wk, Wqkv + (size_t)2048 * 2048, 2048, 512);
  transp_cast<<<dim3(16, 64), dim3(32, 8), 0, stream>>>(Wv, Wqkv + (size_t)2560 * 2048, 2048, 512);
  transp_cast<<<dim3(64, 64), dim3(32, 8), 0, stream>>>(Wo, Wot, 2048, 2048);

  // QKV: M=4096, N=3072 -> 192 blocks, fused RoPE epilogue
  gemm8p<256, 1><<<192, 512, 0, stream>>>(Xb, Wqkv, nullptr, Qb, Kb, Vb,
                                          cosT, sinT, 3072, 2048, 16);
  transp_v<<<dim3(64, 4, 8), dim3(32, 8), 0, stream>>>(Vb, VTb);
  attn_fwd<<<512, 256, 0, stream>>>(Qb, Kb, VTb, AO);
  // out-proj: M=4096, N=2048 -> 256 blocks
  gemm8p<128, 0><<<256, 512, 0, stream>>>(AO, Wot, out, nullptr, nullptr, nullptr,
                                          nullptr, nullptr, 2048, 2048, 32);
}

// Round 10
// 217.245 us; speedup vs baseline: 1.1855x; 1.1855x over previous
//
#include <hip/hip_runtime.h>
#include <hip/hip_bf16.h>

typedef __attribute__((ext_vector_type(8))) short bf16x8;
typedef __attribute__((ext_vector_type(4))) float f32x4;
typedef __attribute__((ext_vector_type(4))) short short4v;

__device__ __forceinline__ unsigned short f2bf(float f) {
  union { float f; unsigned u; } x; x.f = f;
  return (unsigned short)((x.u + 0x7FFFu + ((x.u >> 16) & 1u)) >> 16);
}

__device__ __forceinline__ short f2bf_hw(float f) {
  __hip_bfloat16 h = __float2bfloat16(f);
  return *(short*)&h;
}

__device__ __forceinline__ void lds_cp16(const void* g, void* l) {
  __builtin_amdgcn_global_load_lds(
      (const __attribute__((address_space(1))) void*)g,
      (__attribute__((address_space(3))) void*)l,
      16, 0, 0);
}

#define GBAR() do { __builtin_amdgcn_s_barrier(); __builtin_amdgcn_sched_barrier(0); } while (0)

// ---------------- cast fp32 -> bf16, vectorized ----------------
__global__ __launch_bounds__(256) void cast_x(const float* __restrict__ in,
                                              short* __restrict__ out, int n4) {
  int i = blockIdx.x * 256 + threadIdx.x;
  if (i >= n4) return;
  float4 v = reinterpret_cast<const float4*>(in)[i];
  short4v o;
  o.x = (short)f2bf(v.x); o.y = (short)f2bf(v.y);
  o.z = (short)f2bf(v.z); o.w = (short)f2bf(v.w);
  reinterpret_cast<short4v*>(out)[i] = o;
}

// ---------------- transpose + cast: in KxN fp32 -> out NxK bf16 ----------------
__global__ __launch_bounds__(256) void transp_cast(const float* __restrict__ in,
                                                   short* __restrict__ out,
                                                   int K, int N) {
  __shared__ float t[32][33];
  int bn = blockIdx.x * 32, bk = blockIdx.y * 32;
  int tx = threadIdx.x, ty = threadIdx.y;
  for (int i = ty; i < 32; i += 8)
    t[i][tx] = in[(size_t)(bk + i) * N + bn + tx];
  __syncthreads();
  for (int i = ty; i < 32; i += 8)
    out[(size_t)(bn + i) * K + bk + tx] = (short)f2bf(t[tx][i]);
}

// ---------------- fused Wq/Wk/Wv transpose+cast into Wqkv (NxK, N=3072) -----
__global__ __launch_bounds__(256) void transp_qkv(const float* __restrict__ Wq,
                                                  const float* __restrict__ Wk,
                                                  const float* __restrict__ Wv,
                                                  short* __restrict__ out) {
  __shared__ float t[32][33];
  const int K = 2048;
  int bnG = blockIdx.x * 32;           // output row (= weight col) base, [0,3072)
  int bk = blockIdx.y * 32;
  const float* src; int N, bn;
  if (bnG < 2048)      { src = Wq; N = 2048; bn = bnG; }
  else if (bnG < 2560) { src = Wk; N = 512;  bn = bnG - 2048; }
  else                 { src = Wv; N = 512;  bn = bnG - 2560; }
  int tx = threadIdx.x, ty = threadIdx.y;
  for (int i = ty; i < 32; i += 8)
    t[i][tx] = src[(size_t)(bk + i) * N + bn + tx];
  __syncthreads();
  for (int i = ty; i < 32; i += 8)
    out[(size_t)(bnG + i) * K + bk + tx] = (short)f2bf(t[tx][i]);
}

// ---------------- bf16 transpose: per head [2048 pos][128 dh] -> [128 dh][2048 pos]
__global__ __launch_bounds__(256) void transp_v(const short* __restrict__ V,
                                                short* __restrict__ VTo) {
  __shared__ short t[32][34];
  const int hd = blockIdx.z;
  const int p0 = blockIdx.x * 32, d0 = blockIdx.y * 32;
  const short* src = V + (size_t)hd * 2048 * 128;
  short* dst = VTo + (size_t)hd * 2048 * 128;
  int tx = threadIdx.x, ty = threadIdx.y;
  for (int i = ty; i < 32; i += 8)
    t[i][tx] = src[(size_t)(p0 + i) * 128 + d0 + tx];
  __syncthreads();
  for (int i = ty; i < 32; i += 8)
    dst[(size_t)(d0 + i) * 2048 + p0 + tx] = t[tx][i];
}

// ---------------- 8-wave deep-phase GEMM (unchanged from round 6) ------------
template <int BM, int EPI>
__global__ __launch_bounds__(512, 2) void gemm8p(
    const short* __restrict__ A, const short* __restrict__ Bt,
    float* __restrict__ C,
    short* __restrict__ Qo, short* __restrict__ Ko, short* __restrict__ Vo,
    const float* __restrict__ cosT, const float* __restrict__ sinT,
    int N, int Kd, int nbm) {
  constexpr int NM = BM / 64;
  __shared__ __align__(16) short As[2][BM * 64];
  __shared__ __align__(16) short Bs[2][256 * 64];
  const int tid = threadIdx.x;
  const int l = tid & 63, l15 = l & 15, l4 = l >> 4;
  const int wid = tid >> 6, wr = wid >> 1, wc = wid & 1;
  const int cpx = gridDim.x >> 3;
  const int sid = (blockIdx.x & 7) * cpx + (blockIdx.x >> 3);
  const int bm = sid % nbm, bn = sid / nbm;

  const int srow = tid >> 3;
  const int sch = tid & 7;

  auto stA = [&](int dbuf, int k0, int i) {
    const int rl = srow + i * 64;
    const int c = sch ^ (rl & 7);
    lds_cp16(A + (size_t)(bm * BM + rl) * Kd + k0 + c * 8,
             (char*)As[dbuf] + tid * 16 + i * 8192);
  };
  auto stB = [&](int dbuf, int k0, int j) {
    const int rl = srow + j * 64;
    const int c = sch ^ (rl & 7);
    lds_cp16(Bt + (size_t)(bn * 256 + rl) * Kd + k0 + c * 8,
             (char*)Bs[dbuf] + tid * 16 + j * 8192);
  };
  auto rdA = [&](int dbuf, int m, int kb) {
    const int row = wr * (BM / 4) + m * 16 + l15;
    return *(const bf16x8*)((const char*)As[dbuf] + (row << 7) +
                            ((kb * 64 + l4 * 16) ^ ((row & 7) << 4)));
  };
  auto rdB = [&](int dbuf, int nh, int f, int kb) {
    const int row = wc * 128 + nh * 64 + f * 16 + l15;
    return *(const bf16x8*)((const char*)Bs[dbuf] + (row << 7) +
                            ((kb * 64 + l4 * 16) ^ ((row & 7) << 4)));
  };

  f32x4 acc[NM][8];
#pragma unroll
  for (int m = 0; m < NM; m++)
#pragma unroll
    for (int n = 0; n < 8; n++) acc[m][n] = (f32x4){0.f, 0.f, 0.f, 0.f};

  const int NT = Kd >> 6;

#pragma unroll
  for (int i = 0; i < NM; i++) stA(0, 0, i);
#pragma unroll
  for (int j = 0; j < 4; j++) stB(0, 0, j);
  asm volatile("s_waitcnt vmcnt(0)" ::: "memory");
  GBAR();

  for (int kt = 0; kt < NT; kt++) {
    const int buf = kt & 1, nbf = buf ^ 1;
    const bool stg = (kt + 1 < NT);
    const int k1 = (kt + 1) << 6;
    bf16x8 a[NM], b[4];

    // ---------- phase 0 ----------
#pragma unroll
    for (int m = 0; m < NM; m++) a[m] = rdA(buf, m, 0);
#pragma unroll
    for (int f = 0; f < 4; f++) b[f] = rdB(buf, 0, f, 0);
    if (stg) { stA(nbf, k1, 0); stA(nbf, k1, 1); }
    if (stg) asm volatile("s_waitcnt vmcnt(2)" ::: "memory");
    else     asm volatile("s_waitcnt vmcnt(0)" ::: "memory");
    GBAR();
    asm volatile("s_waitcnt lgkmcnt(0)" ::: "memory");
    __builtin_amdgcn_sched_barrier(0);
    __builtin_amdgcn_s_setprio(1);
#pragma unroll
    for (int m = 0; m < NM; m++)
#pragma unroll
      for (int f = 0; f < 4; f++)
        acc[m][f] = __builtin_amdgcn_mfma_f32_16x16x32_bf16(a[m], b[f], acc[m][f], 0, 0, 0);
    __builtin_amdgcn_s_setprio(0);
    GBAR();

    // ---------- phase 1 ----------
#pragma unroll
    for (int f = 0; f < 4; f++) b[f] = rdB(buf, 1, f, 0);
    if (stg) {
      if (BM == 256) { stA(nbf, k1, 2); stA(nbf, k1, 3); }
      else           { stB(nbf, k1, 0); stB(nbf, k1, 2); }
    }
    GBAR();
    asm volatile("s_waitcnt lgkmcnt(0)" ::: "memory");
    __builtin_amdgcn_sched_barrier(0);
    __builtin_amdgcn_s_setprio(1);
#pragma unroll
    for (int m = 0; m < NM; m++)
#pragma unroll
      for (int f = 0; f < 4; f++)
        acc[m][4 + f] = __builtin_amdgcn_mfma_f32_16x16x32_bf16(a[m], b[f], acc[m][4 + f], 0, 0, 0);
    __builtin_amdgcn_s_setprio(0);
    GBAR();

    // ---------- phase 2 ----------
#pragma unroll
    for (int m = 0; m < NM; m++) a[m] = rdA(buf, m, 1);
#pragma unroll
    for (int f = 0; f < 4; f++) b[f] = rdB(buf, 0, f, 1);
    if (stg) {
      if (BM == 256) { stB(nbf, k1, 0); stB(nbf, k1, 2); }
      else           { stB(nbf, k1, 1); stB(nbf, k1, 3); }
    }
    GBAR();
    asm volatile("s_waitcnt lgkmcnt(0)" ::: "memory");
    __builtin_amdgcn_sched_barrier(0);
    __builtin_amdgcn_s_setprio(1);
#pragma unroll
    for (int m = 0; m < NM; m++)
#pragma unroll
      for (int f = 0; f < 4; f++)
        acc[m][f] = __builtin_amdgcn_mfma_f32_16x16x32_bf16(a[m], b[f], acc[m][f], 0, 0, 0);
    __builtin_amdgcn_s_setprio(0);
    GBAR();

    // ---------- phase 3 ----------
#pragma unroll
    for (int f = 0; f < 4; f++) b[f] = rdB(buf, 1, f, 1);
    if (stg && BM == 256) { stB(nbf, k1, 1); stB(nbf, k1, 3); }
    if (stg) asm volatile("s_waitcnt vmcnt(2)" ::: "memory");
    GBAR();
    asm volatile("s_waitcnt lgkmcnt(0)" ::: "memory");
    __builtin_amdgcn_sched_barrier(0);
    __builtin_amdgcn_s_setprio(1);
#pragma unroll
    for (int m = 0; m < NM; m++)
#pragma unroll
      for (int f = 0; f < 4; f++)
        acc[m][4 + f] = __builtin_amdgcn_mfma_f32_16x16x32_bf16(a[m], b[f], acc[m][4 + f], 0, 0, 0);
    __builtin_amdgcn_s_setprio(0);
    GBAR();
  }

  if (EPI == 0) {
#pragma unroll
    for (int m = 0; m < NM; m++) {
      const int grow = bm * BM + wr * (BM / 4) + m * 16 + l4 * 4;
#pragma unroll
      for (int ni = 0; ni < 8; ni++) {
        const int col = bn * 256 + wc * 128 + (ni >> 2) * 64 + (ni & 3) * 16 + l15;
#pragma unroll
        for (int r = 0; r < 4; r++)
          C[(size_t)(grow + r) * N + col] = acc[m][ni][r];
      }
    }
  } else {
    const int head = bn * 2 + wc;
#pragma unroll
    for (int m = 0; m < NM; m++) {
#pragma unroll
      for (int r = 0; r < 4; r++) {
        const int grow = bm * BM + wr * (BM / 4) + m * 16 + l4 * 4 + r;
        const int bb = grow >> 11, pos = grow & 2047;
        if (head < 20) {
          float c4[4], s4[4];
#pragma unroll
          for (int ni = 0; ni < 4; ni++) {
            const int dh = ni * 16 + l15;
            c4[ni] = cosT[pos * 128 + dh];
            s4[ni] = sinT[pos * 128 + dh];
          }
          short* dst;
          if (head < 16) dst = Qo + ((size_t)(bb * 16 + head) * 2048 + pos) * 128;
          else           dst = Ko + ((size_t)(bb * 4 + (head - 16)) * 2048 + pos) * 128;
#pragma unroll
          for (int ni = 0; ni < 4; ni++) {
            const int dh = ni * 16 + l15;
            float xlo = acc[m][ni][r], xhi = acc[m][ni + 4][r];
            dst[dh]      = (short)f2bf(xlo * c4[ni] - xhi * s4[ni]);
            dst[dh + 64] = (short)f2bf(xhi * c4[ni] + xlo * s4[ni]);
          }
        } else {
          short* dst = Vo + ((size_t)(bb * 4 + (head - 20)) * 2048 + pos) * 128;
#pragma unroll
          for (int ni = 0; ni < 8; ni++)
            dst[(ni >> 2) * 64 + (ni & 3) * 16 + l15] = (short)f2bf(acc[m][ni][r]);
        }
      }
    }
  }
}

// ---------------- flash attention, causal, GQA (round-7 verified version) ----
// 512 blocks (72KB LDS -> 2 blocks/CU, whole grid co-resident), 4 waves.
// Block processes the UNIFORM q-tile pair (pp, 31-pp): 33 kv-tiles each.
// KVBLK=64: K[64][128] + V^T[128][64] double-buffered via global_load_lds
// (pre-swizzled source, XOR (row&7)<<4), no-max softmax, l via ones-MFMA.
// XCD chunking: bid%8 -> 4-bh chunk (single kv-group, K+V 1MB L2-resident).
__global__ __launch_bounds__(256) void attn_fwd(
    const short* __restrict__ Q, const short* __restrict__ K,
    const short* __restrict__ VT, short* __restrict__ AO) {
  __shared__ __align__(16) short Ks[2][64 * 128];
  __shared__ __align__(16) short VTs[2][128 * 64];
  __shared__ __align__(16) short Pl[4][16 * 64];
  const int tid = threadIdx.x;
  const int w = tid >> 6, l = tid & 63;
  const int l15 = l & 15, l4 = l >> 4;
  const int bid = blockIdx.x;
  const int lg = (bid & 7) * 64 + (bid >> 3);   // XCD-chunked logical id
  const int bh = lg >> 4, pp = lg & 15;
  const int b = bh >> 4, h = bh & 15, kv = h >> 2;
  const short* Qbase = Q + (size_t)(b * 16 + h) * 2048 * 128;
  const short* Kbase = K + (size_t)(b * 4 + kv) * 2048 * 128;
  const short* VTb   = VT + (size_t)(b * 4 + kv) * 2048 * 128;

  int rk[4], ck[4], dv[4], kc[4];
#pragma unroll
  for (int i = 0; i < 4; i++) {
    const int c = tid + i * 256;
    rk[i] = c >> 4; ck[i] = (c & 15) ^ (rk[i] & 7);
    dv[i] = c >> 3; kc[i] = (c & 7) ^ (dv[i] & 7);
  }

  const float SCL = 0.08838834764831845f * 1.4426950408889634f;  // 1/sqrt(128)*log2e

  bf16x8 ones;
#pragma unroll
  for (int j = 0; j < 8; j++) ones[j] = (short)0x3F80;

  for (int qq = 0; qq < 2; qq++) {
    const int qt = qq ? (31 - pp) : pp;
    const int q0w = qt * 64 + w * 16;

    bf16x8 qf[4];
#pragma unroll
    for (int kb = 0; kb < 4; kb++)
      qf[kb] = *(const bf16x8*)(Qbase + (size_t)(q0w + l15) * 128 + kb * 32 + l4 * 8);

    f32x4 oacc[8];
#pragma unroll
    for (int i = 0; i < 8; i++) oacc[i] = (f32x4){0.f, 0.f, 0.f, 0.f};
    f32x4 lacc = (f32x4){0.f, 0.f, 0.f, 0.f};

    const int ntiles = qt + 1;

    __syncthreads();  // prior q-tile's LDS reads done before restaging
#pragma unroll
    for (int i = 0; i < 4; i++) {
      lds_cp16(Kbase + rk[i] * 128 + ck[i] * 8, (char*)Ks[0] + i * 4096 + tid * 16);
      lds_cp16(VTb + (size_t)dv[i] * 2048 + kc[i] * 8, (char*)VTs[0] + i * 4096 + tid * 16);
    }

    for (int nt = 0; nt < ntiles; nt++) {
      const int k0 = nt * 64, buf = nt & 1;
      __syncthreads();  // drains own vmcnt -> tile nt resident for all waves
      if (nt + 1 < ntiles) {
        const int kn = k0 + 64, bnx = buf ^ 1;
#pragma unroll
        for (int i = 0; i < 4; i++) {
          lds_cp16(Kbase + (size_t)(kn + rk[i]) * 128 + ck[i] * 8,
                   (char*)Ks[bnx] + i * 4096 + tid * 16);
          lds_cp16(VTb + (size_t)dv[i] * 2048 + kn + kc[i] * 8,
                   (char*)VTs[bnx] + i * 4096 + tid * 16);
        }
      }

      // S = Q @ K^T : 16 q-rows x 64 keys per wave
      f32x4 sa[4];
#pragma unroll
      for (int kg = 0; kg < 4; kg++) sa[kg] = (f32x4){0.f, 0.f, 0.f, 0.f};
      __builtin_amdgcn_s_setprio(1);
#pragma unroll
      for (int kg = 0; kg < 4; kg++) {
        const int row = kg * 16 + l15;
        const int swz = (row & 7) << 4;
#pragma unroll
        for (int kb = 0; kb < 4; kb++) {
          const char* kp = (const char*)Ks[buf] + row * 256 + ((kb * 64 + l4 * 16) ^ swz);
          sa[kg] = __builtin_amdgcn_mfma_f32_16x16x32_bf16(qf[kb], *(const bf16x8*)kp, sa[kg], 0, 0, 0);
        }
      }
      __builtin_amdgcn_s_setprio(0);

      // P = exp(s*scale); mask only the diagonal tile
      float p[4][4];
      const bool domask = (k0 + 63 > q0w);
#pragma unroll
      for (int kg = 0; kg < 4; kg++)
#pragma unroll
        for (int r = 0; r < 4; r++) {
          float pv = exp2f(sa[kg][r] * SCL);
          if (domask) {
            int qrow = q0w + l4 * 4 + r;
            if (k0 + kg * 16 + l15 > qrow) pv = 0.f;
          }
          p[kg][r] = pv;
        }

      // P: C-layout -> A-layout via per-wave swizzled LDS
#pragma unroll
      for (int r = 0; r < 4; r++) {
        const int rw = l4 * 4 + r;
        const int swz = (rw & 7) << 4;
#pragma unroll
        for (int kg = 0; kg < 4; kg++)
          *(short*)((char*)Pl[w] + (rw * 128 + ((kg * 32 + l15 * 2) ^ swz))) =
              f2bf_hw(p[kg][r]);
      }
      asm volatile("s_waitcnt lgkmcnt(0)" ::: "memory");
      bf16x8 pf[2];
#pragma unroll
      for (int ks = 0; ks < 2; ks++)
        pf[ks] = *(const bf16x8*)((const char*)Pl[w] +
                 (l15 * 128 + ((ks * 64 + l4 * 16) ^ ((l15 & 7) << 4))));

      // O += P @ V^T ; l += P @ ones
      __builtin_amdgcn_s_setprio(1);
#pragma unroll
      for (int nb = 0; nb < 8; nb++) {
        const int d = nb * 16 + l15;
        const int dsw = (d & 7) << 4;
#pragma unroll
        for (int ks = 0; ks < 2; ks++) {
          const char* vp = (const char*)VTs[buf] + d * 128 + ((ks * 64 + l4 * 16) ^ dsw);
          oacc[nb] = __builtin_amdgcn_mfma_f32_16x16x32_bf16(pf[ks], *(const bf16x8*)vp, oacc[nb], 0, 0, 0);
        }
      }
      lacc = __builtin_amdgcn_mfma_f32_16x16x32_bf16(pf[0], ones, lacc, 0, 0, 0);
      lacc = __builtin_amdgcn_mfma_f32_16x16x32_bf16(pf[1], ones, lacc, 0, 0, 0);
      __builtin_amdgcn_s_setprio(0);
    }

    // epilogue: normalize by l, write bf16 AO [B][L][H*Dh]
#pragma unroll
    for (int r = 0; r < 4; r++) {
      float inv = 1.0f / lacc[r];
      size_t rowb = ((size_t)b * 2048 + q0w + l4 * 4 + r) * 2048 + h * 128;
#pragma unroll
      for (int nb = 0; nb < 8; nb++)
        AO[rowb + nb * 16 + l15] = f2bf_hw(oacc[nb][r] * inv);
    }
  }
}

extern "C" void kernel_launch(void* const* d_in, const int* in_sizes, int n_in,
                              void* d_out, int out_size, void* d_ws, size_t ws_size,
                              hipStream_t stream) {
  const float* hs   = (const float*)d_in[0];
  const float* cosT = (const float*)d_in[1];
  const float* sinT = (const float*)d_in[2];
  const float* Wq   = (const float*)d_in[3];
  const float* Wk   = (const float*)d_in[4];
  const float* Wv   = (const float*)d_in[5];
  const float* Wo   = (const float*)d_in[6];
  float* out = (float*)d_out;

  char* p = (char*)d_ws;
  short* Xb   = (short*)p; p += (size_t)4096 * 2048 * 2;   // reused as AO
  short* Wqkv = (short*)p; p += (size_t)3072 * 2048 * 2;
  short* Wot  = (short*)p; p += (size_t)2048 * 2048 * 2;
  short* Qb   = (short*)p; p += (size_t)2 * 16 * 2048 * 128 * 2;
  short* Kb   = (short*)p; p += (size_t)2 * 4 * 2048 * 128 * 2;
  short* Vb   = (short*)p; p += (size_t)2 * 4 * 2048 * 128 * 2;
  short* VTb  = (short*)p; p += (size_t)2 * 4 * 2048 * 128 * 2;
  short* AO   = Xb;

  cast_x<<<8192, 256, 0, stream>>>(hs, Xb, 2097152);
  transp_qkv<<<dim3(96, 64), dim3(32, 8), 0, stream>>>(Wq, Wk, Wv, Wqkv);
  transp_cast<<<dim3(64, 64), dim3(32, 8), 0, stream>>>(Wo, Wot, 2048, 2048);

  // QKV: M=4096, N=3072 -> 192 blocks, fused RoPE epilogue
  gemm8p<256, 1><<<192, 512, 0, stream>>>(Xb, Wqkv, nullptr, Qb, Kb, Vb,
                                          cosT, sinT, 3072, 2048, 16);
  transp_v<<<dim3(64, 4, 8), dim3(32, 8), 0, stream>>>(Vb, VTb);
  attn_fwd<<<512, 256, 0, stream>>>(Qb, Kb, VTb, AO);
  // out-proj: M=4096, N=2048 -> 256 blocks
  gemm8p<128, 0><<<256, 512, 0, stream>>>(AO, Wot, out, nullptr, nullptr, nullptr,
                                          nullptr, nullptr, 2048, 2048, 32);
}